// Round 1
// 2374.896 us; speedup vs baseline: 1.0855x; 1.0855x over previous
//
#include <hip/hip_runtime.h>
#include <hip/hip_bf16.h>
#include <math.h>

#define B_   16384
#define NT   10
#define KNN  5
#define D_   512
#define MTOT (B_*NT)   // 163840

typedef __bf16 bf;
typedef __bf16 bfrag8 __attribute__((ext_vector_type(8)));
typedef float  floatx4 __attribute__((ext_vector_type(4)));

__device__ __forceinline__ float tof(bf x) { return (float)x; }
__device__ __forceinline__ bf    tob(float x) { return (bf)x; }

#define GLD_LDS(g, l) __builtin_amdgcn_global_load_lds( \
    (const __attribute__((address_space(1))) void*)(g), \
    (__attribute__((address_space(3))) void*)(l), 16, 0, 0)

// ---------------------------------------------------------------------------
// Fold kernel (f32 inputs -> bf16 folded weights):
// At_h[n,k] = (Wq_h^T Wk_h / 16)^T ; Ct_h[d,k] = (Wv_h^T Wo_h')^T
// wconst[d] = bo[d] + sum_e bv[e]*wo[d,e] ; uvec_h[k] = Wk_h^T bq_h / 16
// ---------------------------------------------------------------------------
__global__ void prep_folds(const float* __restrict__ wqkv, const float* __restrict__ bqkv,
                           const float* __restrict__ wo,   const float* __restrict__ bo,
                           bf* __restrict__ At, bf* __restrict__ Ct,
                           float* __restrict__ wconst, float* __restrict__ uvec)
{
    int gid = blockIdx.x, tid = threadIdx.x;
    if (gid < 4096) {
        int idx = gid * 256 + tid;           // 0 .. 4*262144-1
        int mat = idx >> 18;
        int rem = idx & 262143;
        int row = rem >> 9, col = rem & 511;
        float acc = 0.f;
        if (mat < 2) {
            int h = mat;
            const float* wq = wqkv + (size_t)(h * 256) * 512;
            const float* wk = wqkv + (size_t)(512 + h * 256) * 512;
            for (int c = 0; c < 256; ++c)
                acc += wq[c * 512 + col] * wk[c * 512 + row];
            At[(size_t)h * 262144 + row * 512 + col] = tob(acc * 0.0625f);
        } else {
            int h = mat - 2;
            const float* wv = wqkv + (size_t)(1024 + h * 256) * 512;
            for (int e = 0; e < 256; ++e)
                acc += wv[e * 512 + col] * wo[row * 512 + h * 256 + e];
            Ct[(size_t)h * 262144 + row * 512 + col] = tob(acc);
        }
    } else {
        for (int d = tid; d < 512; d += 256) {
            float acc = bo[d];
            for (int e = 0; e < 512; ++e)
                acc += bqkv[1024 + e] * wo[d * 512 + e];
            wconst[d] = acc;
            for (int h = 0; h < 2; ++h) {
                float u = 0.f;
                for (int c = 0; c < 256; ++c)
                    u += wqkv[(size_t)(512 + h * 256 + c) * 512 + d] * bqkv[h * 256 + c];
                uvec[h * 512 + d] = u * 0.0625f;
            }
        }
    }
}

// ---------------------------------------------------------------------------
// cvt_w: cast f32 [512,512] weight to bf16 (row-major preserved)
// ---------------------------------------------------------------------------
__global__ void cvt_w(const float* __restrict__ src, bf* __restrict__ dst)
{
    int i = blockIdx.x * 256 + threadIdx.x;     // 262144/4 threads, float4 each
    float4 v = *(const float4*)(src + (size_t)i * 4);
    bf o[4] = { tob(v.x), tob(v.y), tob(v.z), tob(v.w) };
    *(unsigned long long*)(dst + (size_t)i * 4) = *(unsigned long long*)o;
}

// ---------------------------------------------------------------------------
// rel: boxes (f32) -> per-token K-NN relative features [MTOT, 20] (f32)
// fp contract off: match numpy's round-per-op f32 so argmin ties match ref
// ---------------------------------------------------------------------------
__global__ void rel_kernel(const float* __restrict__ boxes, float* __restrict__ rel)
{
#pragma clang fp contract(off)
    int gid = blockIdx.x * blockDim.x + threadIdx.x;
    if (gid >= MTOT) return;
    int b = gid / NT, n = gid % NT;
    const float* bx = boxes + (size_t)b * NT * 4;
    float cx[NT], cy[NT], bw[NT], bh[NT];
#pragma unroll
    for (int j = 0; j < NT; ++j) {
        float x0 = bx[j * 4 + 0], y0 = bx[j * 4 + 1];
        float x1 = bx[j * 4 + 2], y1 = bx[j * 4 + 3];
        cx[j] = ((x0 + x1) * 0.5f) * (1.f / 512.f);
        cy[j] = ((y0 + y1) * 0.5f) * (1.f / 512.f);
        bw[j] = fabsf(x1 - x0) * (1.f / 512.f);
        bh[j] = fabsf(y1 - y0) * (1.f / 512.f);
    }
    float dist[NT];
#pragma unroll
    for (int j = 0; j < NT; ++j) {
        float dx = cx[n] - cx[j], dy = cy[n] - cy[j];
        float dxx = dx * dx, dyy = dy * dy;
        dist[j] = (j == n) ? __builtin_inff() : (dxx + dyy);
    }
    float ocx = cx[n], ocy = cy[n], obw = bw[n], obh = bh[n];
#pragma unroll
    for (int k = 0; k < KNN; ++k) {
        int best = 0; float bd = __builtin_inff();
#pragma unroll
        for (int j = 0; j < NT; ++j)
            if (dist[j] < bd) { bd = dist[j]; best = j; }   // strict <  == lowest-index tie-break
        float fx = 0, fy = 0, fw = 0, fh = 0;
#pragma unroll
        for (int j = 0; j < NT; ++j)
            if (j == best) { fx = cx[j]; fy = cy[j]; fw = bw[j]; fh = bh[j]; dist[j] = __builtin_inff(); }
        size_t o = (size_t)gid * 20 + k * 4;
        rel[o + 0] = fx - ocx;
        rel[o + 1] = fy - ocy;
        rel[o + 2] = fw - obw;
        rel[o + 3] = fh - obh;
    }
}

// ---------------------------------------------------------------------------
// gemm_in: x0 = rel @ w_in^T + b_in   [MTOT,20] @ [20,512], f32 -> bf16
// ---------------------------------------------------------------------------
__global__ void gemm_in(const float* __restrict__ rel, const float* __restrict__ w_in,
                        const float* __restrict__ b_in, bf* __restrict__ x0)
{
    __shared__ float relS[128][20];
    int tid = threadIdx.x;
    size_t tok0 = (size_t)blockIdx.x * 128;
    for (int i = tid; i < 128 * 20; i += 256)
        relS[i / 20][i % 20] = rel[tok0 * 20 + i];
    float w0[20], w1r[20];
#pragma unroll
    for (int j = 0; j < 20; ++j) {
        w0[j]  = w_in[tid * 20 + j];
        w1r[j] = w_in[(tid + 256) * 20 + j];
    }
    float bias0 = b_in[tid], bias1 = b_in[tid + 256];
    __syncthreads();
    for (int tk = 0; tk < 128; ++tk) {
        float a0 = bias0, a1 = bias1;
#pragma unroll
        for (int j = 0; j < 20; ++j) {
            float r = relS[tk][j];
            a0 += r * w0[j];
            a1 += r * w1r[j];
        }
        x0[(tok0 + tk) * 512 + tid]       = tob(a0);
        x0[(tok0 + tk) * 512 + tid + 256] = tob(a1);
    }
}

// ---------------------------------------------------------------------------
// gemm_fn: out[m,n] = sum_k A[m,k]*Bt[n,k] (+epilogue), M=163840, N=K=512
// Full-N blocks: BM=128, BN=512, BK=32. 512 thr = 8 waves, each 64x128 out.
// Double-buffered LDS (80 KB), T3-minimum 2-phase pipeline:
//   STAGE(next) ; ds_read+MFMA(cur) ; s_waitcnt vmcnt(0) lgkmcnt(0) ; barrier
// A fetched from HBM exactly once (no grid.x split); B (512 KB) rides in L2.
// EPI: 0 none | 1 f32 bias + exact gelu | 2 f32 bias | 3 add prev out
// ---------------------------------------------------------------------------
template <int EPI>
__launch_bounds__(512, 2)
__global__ void gemm_fn(const bf* __restrict__ A, const bf* __restrict__ Bt,
                        bf* __restrict__ out, const float* __restrict__ biasf)
{
    // chunked [kc][row][8] layout: conflict-free ds_read_b128 + linear GLD dest
    __shared__ bf As[2][128 * 32];
    __shared__ bf Bs[2][512 * 32];
    int tid = threadIdx.x;
    int w = tid >> 6, l = tid & 63;
    int lq = l >> 4, lr = l & 15;
    size_t m0 = (size_t)blockIdx.x * 128;
    int wm = (w & 1) * 64, wn = (w >> 1) * 128;
    floatx4 acc[4][8] = {};

    // per-thread global staging addresses
    const bf* Ag = A + (m0 + (tid & 127)) * 512 + (tid >> 7) * 8;
    const bf* Bg = Bt + (size_t)tid * 512;

    auto stage = [&](int buf, int kt) {
        // A tile: 128x32 -> As[kc=tid>>7][row=tid&127][8], dest = wave base + lane*16
        GLD_LDS(Ag + kt * 32, &As[buf][w * 512]);
        // B tile: 512x32 -> Bs[kc=p][row=tid][8]
#pragma unroll
        for (int p = 0; p < 4; ++p)
            GLD_LDS(Bg + kt * 32 + p * 8, &Bs[buf][(p * 512 + w * 64) * 8]);
    };

    stage(0, 0);
    asm volatile("s_waitcnt vmcnt(0)" ::: "memory");
    __builtin_amdgcn_s_barrier();
    __builtin_amdgcn_sched_barrier(0);

#pragma unroll 2
    for (int kt = 0; kt < 16; ++kt) {
        int cur = kt & 1;
        if (kt < 15) stage(cur ^ 1, kt + 1);

        const bf* as = &As[cur][(lq * 128 + wm + lr) * 8];
        const bf* bs = &Bs[cur][(lq * 512 + wn + lr) * 8];
        bfrag8 af[4], bfv[8];
#pragma unroll
        for (int i = 0; i < 4; ++i)
            af[i] = *(const bfrag8*)(as + i * 16 * 8);
#pragma unroll
        for (int j = 0; j < 8; ++j)
            bfv[j] = *(const bfrag8*)(bs + j * 16 * 8);
#pragma unroll
        for (int i = 0; i < 4; ++i)
#pragma unroll
            for (int j = 0; j < 8; ++j)
                acc[i][j] = __builtin_amdgcn_mfma_f32_16x16x32_bf16(af[i], bfv[j], acc[i][j], 0, 0, 0);

        if (kt < 15) {
            asm volatile("s_waitcnt vmcnt(0) lgkmcnt(0)" ::: "memory");
            __builtin_amdgcn_s_barrier();
            __builtin_amdgcn_sched_barrier(0);
        }
    }

#pragma unroll
    for (int i = 0; i < 4; ++i)
#pragma unroll
        for (int j = 0; j < 8; ++j) {
            int col = wn + j * 16 + lr;
#pragma unroll
            for (int r = 0; r < 4; ++r) {
                int row = wm + i * 16 + lq * 4 + r;
                float v = acc[i][j][r];
                if (EPI == 1) { v += biasf[col]; v = 0.5f * v * (1.f + erff(v * 0.70710678118654752f)); }
                if (EPI == 2) v += biasf[col];
                if (EPI == 3) v += tof(out[(m0 + row) * 512 + col]);
                out[(m0 + row) * 512 + col] = tob(v);
            }
        }
}

// ---------------------------------------------------------------------------
// scores: per (batch,head): S = t_b @ x0_b^T (+ x0@uvec bias), softmax -> att
// one wave per batch; MFMA 16x16x32 over K=512
// ---------------------------------------------------------------------------
__global__ void scores_kernel(const bf* __restrict__ t, const bf* __restrict__ x0,
                              const float* __restrict__ uvec_h, float* __restrict__ att)
{
    int tid = threadIdx.x;
    int w = tid >> 6, l = tid & 63;
    int lq = l >> 4, lr = l & 15;
    size_t b = (size_t)blockIdx.x * 4 + w;
    const bf* trow = t  + (b * NT + lr) * 512;   // lr>=10 overruns into pad rows (allocated)
    const bf* xrow = x0 + (b * NT + lr) * 512;
    floatx4 acc = {0.f, 0.f, 0.f, 0.f};
    float xu = 0.f;
#pragma unroll
    for (int kk = 0; kk < 16; ++kk) {
        bfrag8 a  = *(const bfrag8*)(trow + kk * 32 + lq * 8);
        bfrag8 bb = *(const bfrag8*)(xrow + kk * 32 + lq * 8);
        acc = __builtin_amdgcn_mfma_f32_16x16x32_bf16(a, bb, acc, 0, 0, 0);
#pragma unroll
        for (int jj = 0; jj < 8; ++jj)
            xu += (float)bb[jj] * uvec_h[kk * 32 + lq * 8 + jj];
    }
    xu += __shfl_xor(xu, 16);
    xu += __shfl_xor(xu, 32);    // xu for column j = lr
    bool jvalid = (lr < NT);
    float* ab = att + b * 100;
#pragma unroll
    for (int r = 0; r < 4; ++r) {
        float v = jvalid ? (acc[r] + xu) : -__builtin_inff();
        float m = v;
        m = fmaxf(m, __shfl_xor(m, 1)); m = fmaxf(m, __shfl_xor(m, 2));
        m = fmaxf(m, __shfl_xor(m, 4)); m = fmaxf(m, __shfl_xor(m, 8));
        float e = jvalid ? __expf(v - m) : 0.f;
        float s = e;
        s += __shfl_xor(s, 1); s += __shfl_xor(s, 2);
        s += __shfl_xor(s, 4); s += __shfl_xor(s, 8);
        float a = e / s;
        int i = lq * 4 + r;
        if (jvalid && i < NT) ab[i * 10 + lr] = a;
    }
}

// ---------------------------------------------------------------------------
// zmix: z = att_h @ x0 per batch  ([10,10]@[10,512])
// ---------------------------------------------------------------------------
__global__ void zmix(const float* __restrict__ att, const bf* __restrict__ x0, bf* __restrict__ z)
{
    __shared__ float xs[NT][512];
    __shared__ float as[100];
    size_t b = blockIdx.x;
    int tid = threadIdx.x;
    const bf* xb = x0 + b * NT * 512;
    for (int i = tid; i < NT * 512; i += 256) xs[i >> 9][i & 511] = tof(xb[i]);
    for (int i = tid; i < 100; i += 256) as[i] = att[b * 100 + i];
    __syncthreads();
    bf* zb = z + b * NT * 512;
    for (int o = tid; o < NT * 512; o += 256) {
        int i = o >> 9, d = o & 511;
        float a = 0.f;
#pragma unroll
        for (int j = 0; j < NT; ++j) a += as[i * 10 + j] * xs[j][d];
        zb[o] = tob(a);
    }
}

// ---------------------------------------------------------------------------
// ln: xout = LN(xin + yin) * w + b   (one wave per token), f32 LN params
// ---------------------------------------------------------------------------
__global__ void ln_kernel(const bf* __restrict__ xin, const bf* __restrict__ yin,
                          const float* __restrict__ w, const float* __restrict__ bias,
                          bf* __restrict__ xout)
{
    int tid = threadIdx.x;
    int wv = tid >> 6, l = tid & 63;
    size_t tok = (size_t)blockIdx.x * 4 + wv;
    bfrag8 xv = *(const bfrag8*)(xin + tok * 512 + l * 8);
    bfrag8 yv = *(const bfrag8*)(yin + tok * 512 + l * 8);
    float v[8]; float s = 0.f;
#pragma unroll
    for (int i = 0; i < 8; ++i) { v[i] = (float)xv[i] + (float)yv[i]; s += v[i]; }
#pragma unroll
    for (int m = 1; m < 64; m <<= 1) s += __shfl_xor(s, m);
    float mu = s * (1.f / 512.f);
    float vs = 0.f;
#pragma unroll
    for (int i = 0; i < 8; ++i) { float d = v[i] - mu; vs += d * d; }
#pragma unroll
    for (int m = 1; m < 64; m <<= 1) vs += __shfl_xor(vs, m);
    float r = rsqrtf(vs * (1.f / 512.f) + 1e-5f);
    bfrag8 ov;
#pragma unroll
    for (int i = 0; i < 8; ++i) {
        int d = l * 8 + i;
        ov[i] = tob((v[i] - mu) * r * w[d] + bias[d]);
    }
    *(bfrag8*)(xout + tok * 512 + l * 8) = ov;
}

// ---------------------------------------------------------------------------
// final: out = LN( LN(x1 + ff2; ln2); lnf )   -> f32 output
// ---------------------------------------------------------------------------
__global__ void final_kernel(const bf* __restrict__ x1, const bf* __restrict__ ff2,
                             const float* __restrict__ w2, const float* __restrict__ b2,
                             const float* __restrict__ wf, const float* __restrict__ bfi,
                             float* __restrict__ out)
{
    int tid = threadIdx.x;
    int wv = tid >> 6, l = tid & 63;
    size_t tok = (size_t)blockIdx.x * 4 + wv;
    bfrag8 xv = *(const bfrag8*)(x1 + tok * 512 + l * 8);
    bfrag8 yv = *(const bfrag8*)(ff2 + tok * 512 + l * 8);
    float v[8]; float s = 0.f;
#pragma unroll
    for (int i = 0; i < 8; ++i) { v[i] = (float)xv[i] + (float)yv[i]; s += v[i]; }
#pragma unroll
    for (int m = 1; m < 64; m <<= 1) s += __shfl_xor(s, m);
    float mu = s * (1.f / 512.f);
    float vs = 0.f;
#pragma unroll
    for (int i = 0; i < 8; ++i) { float d = v[i] - mu; vs += d * d; }
#pragma unroll
    for (int m = 1; m < 64; m <<= 1) vs += __shfl_xor(vs, m);
    float r = rsqrtf(vs * (1.f / 512.f) + 1e-5f);
    float u[8]; float s2 = 0.f;
#pragma unroll
    for (int i = 0; i < 8; ++i) {
        int d = l * 8 + i;
        u[i] = (v[i] - mu) * r * w2[d] + b2[d];
        s2 += u[i];
    }
#pragma unroll
    for (int m = 1; m < 64; m <<= 1) s2 += __shfl_xor(s2, m);
    float mu2 = s2 * (1.f / 512.f);
    float vs2 = 0.f;
#pragma unroll
    for (int i = 0; i < 8; ++i) { float d = u[i] - mu2; vs2 += d * d; }
#pragma unroll
    for (int m = 1; m < 64; m <<= 1) vs2 += __shfl_xor(vs2, m);
    float r2 = rsqrtf(vs2 * (1.f / 512.f) + 1e-5f);
    float4 o0, o1;
    float* op = (float*)&o0;
#pragma unroll
    for (int i = 0; i < 4; ++i) op[i] = (u[i] - mu2) * r2 * wf[l * 8 + i] + bfi[l * 8 + i];
    op = (float*)&o1;
#pragma unroll
    for (int i = 0; i < 4; ++i) op[i] = (u[4 + i] - mu2) * r2 * wf[l * 8 + 4 + i] + bfi[l * 8 + 4 + i];
    *(float4*)(out + tok * 512 + l * 8) = o0;
    *(float4*)(out + tok * 512 + l * 8 + 4) = o1;
}

// ---------------------------------------------------------------------------
extern "C" void kernel_launch(void* const* d_in, const int* in_sizes, int n_in,
                              void* d_out, int out_size, void* d_ws, size_t ws_size,
                              hipStream_t stream)
{
    const float* boxes = (const float*)d_in[0];
    const float* w_in  = (const float*)d_in[1];
    const float* b_in  = (const float*)d_in[2];
    const float* wqkv  = (const float*)d_in[3];
    const float* bqkv  = (const float*)d_in[4];
    const float* wo    = (const float*)d_in[5];
    const float* bo    = (const float*)d_in[6];
    const float* ln1w  = (const float*)d_in[7];
    const float* ln1b  = (const float*)d_in[8];
    const float* w1    = (const float*)d_in[9];
    const float* b1    = (const float*)d_in[10];
    const float* w2    = (const float*)d_in[11];
    const float* b2    = (const float*)d_in[12];
    const float* ln2w  = (const float*)d_in[13];
    const float* ln2b  = (const float*)d_in[14];
    const float* lnfw  = (const float*)d_in[15];
    const float* lnfb  = (const float*)d_in[16];
    float* out = (float*)d_out;

    char* ws = (char*)d_ws;
    // layout (bytes), total ≈ 519.6 MB:
    bf*    At     = (bf*)(ws + 0);                            //  1,048,576
    bf*    Ct     = (bf*)(ws + 1048576);                      //  1,048,576
    bf*    W1b    = (bf*)(ws + 2097152);                      //  524,288
    bf*    W2b    = (bf*)(ws + 2621440);                      //  524,288
    float* wconst = (float*)(ws + 3145728);                   //  2,048
    float* uvec   = (float*)(ws + 3147776);                   //  4,096
    float* att    = (float*)(ws + 3151872);                   //  13,107,200
    bf*    x0     = (bf*)(ws + 16259072);                     //  (MTOT+16)*512*2
    bf*    t      = (bf*)(ws + 184047616);                    //  (MTOT+16)*512*2
    bf*    y      = (bf*)(ws + 351836160);                    //  MTOT*512*2
    float* rel    = (float*)(ws + 184047616);                 //  overlays t (disjoint lifetime)

    dim3 gblk(256);
    dim3 gfn(MTOT / 128);     // 1280 full-width GEMM blocks

    prep_folds<<<4097, gblk, 0, stream>>>(wqkv, bqkv, wo, bo, At, Ct, wconst, uvec);
    cvt_w<<<256, gblk, 0, stream>>>(w1, W1b);
    cvt_w<<<256, gblk, 0, stream>>>(w2, W2b);
    rel_kernel<<<(MTOT + 255) / 256, gblk, 0, stream>>>(boxes, rel);
    gemm_in<<<MTOT / 128, gblk, 0, stream>>>(rel, w_in, b_in, x0);

    // head 0 scores
    gemm_fn<0><<<gfn, 512, 0, stream>>>(x0, At, t, nullptr);
    scores_kernel<<<B_ / 4, gblk, 0, stream>>>(t, x0, uvec, att);
    // head 1 scores
    gemm_fn<0><<<gfn, 512, 0, stream>>>(x0, At + 262144, t, nullptr);
    scores_kernel<<<B_ / 4, gblk, 0, stream>>>(t, x0, uvec + 512, att + (size_t)B_ * 100);
    // attn out: y = (att0@x0)@Ct0 + wconst ; y += (att1@x0)@Ct1
    zmix<<<B_, gblk, 0, stream>>>(att, x0, t);
    gemm_fn<2><<<gfn, 512, 0, stream>>>(t, Ct, y, wconst);
    zmix<<<B_, gblk, 0, stream>>>(att + (size_t)B_ * 100, x0, t);
    gemm_fn<3><<<gfn, 512, 0, stream>>>(t, Ct + 262144, y, nullptr);
    // x1 = LN(x0 + y) (in place into x0)
    ln_kernel<<<MTOT / 4, gblk, 0, stream>>>(x0, y, ln1w, ln1b, x0);
    // ff1 = gelu(x1@w1^T + b1) -> t ; ff2 = ff1@w2^T + b2 -> y
    gemm_fn<1><<<gfn, 512, 0, stream>>>(x0, W1b, t, b1);
    gemm_fn<2><<<gfn, 512, 0, stream>>>(t, W2b, y, b2);
    // out = LN(LN(x1+ff2; ln2); lnf)
    final_kernel<<<MTOT / 4, gblk, 0, stream>>>(x0, y, ln2w, ln2b, lnfw, lnfb, out);
}

// Round 3
// 2172.236 us; speedup vs baseline: 1.1867x; 1.0933x over previous
//
#include <hip/hip_runtime.h>
#include <hip/hip_bf16.h>
#include <math.h>

#define B_   16384
#define NT   10
#define KNN  5
#define D_   512
#define MTOT (B_*NT)   // 163840

typedef __bf16 bf;
typedef __bf16 bfrag8 __attribute__((ext_vector_type(8)));
typedef float  floatx4 __attribute__((ext_vector_type(4)));

__device__ __forceinline__ float tof(bf x) { return (float)x; }
__device__ __forceinline__ bf    tob(float x) { return (bf)x; }

#define GLD_LDS(g, l) __builtin_amdgcn_global_load_lds( \
    (const __attribute__((address_space(1))) void*)(g), \
    (__attribute__((address_space(3))) void*)(l), 16, 0, 0)

// ---------------------------------------------------------------------------
// Fold kernel (f32 inputs -> bf16 folded weights):
// At_h[n,k] = (Wq_h^T Wk_h / 16)^T ; Ct_h[d,k] = (Wv_h^T Wo_h')^T
// wconst[d] = bo[d] + sum_e bv[e]*wo[d,e] ; uvec_h[k] = Wk_h^T bq_h / 16
// ---------------------------------------------------------------------------
__global__ void prep_folds(const float* __restrict__ wqkv, const float* __restrict__ bqkv,
                           const float* __restrict__ wo,   const float* __restrict__ bo,
                           bf* __restrict__ At, bf* __restrict__ Ct,
                           float* __restrict__ wconst, float* __restrict__ uvec)
{
    int gid = blockIdx.x, tid = threadIdx.x;
    if (gid < 4096) {
        int idx = gid * 256 + tid;           // 0 .. 4*262144-1
        int mat = idx >> 18;
        int rem = idx & 262143;
        int row = rem >> 9, col = rem & 511;
        float acc = 0.f;
        if (mat < 2) {
            int h = mat;
            const float* wq = wqkv + (size_t)(h * 256) * 512;
            const float* wk = wqkv + (size_t)(512 + h * 256) * 512;
            for (int c = 0; c < 256; ++c)
                acc += wq[c * 512 + col] * wk[c * 512 + row];
            At[(size_t)h * 262144 + row * 512 + col] = tob(acc * 0.0625f);
        } else {
            int h = mat - 2;
            const float* wv = wqkv + (size_t)(1024 + h * 256) * 512;
            for (int e = 0; e < 256; ++e)
                acc += wv[e * 512 + col] * wo[row * 512 + h * 256 + e];
            Ct[(size_t)h * 262144 + row * 512 + col] = tob(acc);
        }
    } else {
        for (int d = tid; d < 512; d += 256) {
            float acc = bo[d];
            for (int e = 0; e < 512; ++e)
                acc += bqkv[1024 + e] * wo[d * 512 + e];
            wconst[d] = acc;
            for (int h = 0; h < 2; ++h) {
                float u = 0.f;
                for (int c = 0; c < 256; ++c)
                    u += wqkv[(size_t)(512 + h * 256 + c) * 512 + d] * bqkv[h * 256 + c];
                uvec[h * 512 + d] = u * 0.0625f;
            }
        }
    }
}

// ---------------------------------------------------------------------------
// cvt_w: cast f32 [512,512] weight to bf16 (row-major preserved)
// ---------------------------------------------------------------------------
__global__ void cvt_w(const float* __restrict__ src, bf* __restrict__ dst)
{
    int i = blockIdx.x * 256 + threadIdx.x;     // 262144/4 threads, float4 each
    float4 v = *(const float4*)(src + (size_t)i * 4);
    bf o[4] = { tob(v.x), tob(v.y), tob(v.z), tob(v.w) };
    *(unsigned long long*)(dst + (size_t)i * 4) = *(unsigned long long*)o;
}

// ---------------------------------------------------------------------------
// rel: boxes (f32) -> per-token K-NN relative features [MTOT, 20] (f32)
// fp contract off: match numpy's round-per-op f32 so argmin ties match ref
// ---------------------------------------------------------------------------
__global__ void rel_kernel(const float* __restrict__ boxes, float* __restrict__ rel)
{
#pragma clang fp contract(off)
    int gid = blockIdx.x * blockDim.x + threadIdx.x;
    if (gid >= MTOT) return;
    int b = gid / NT, n = gid % NT;
    const float* bx = boxes + (size_t)b * NT * 4;
    float cx[NT], cy[NT], bw[NT], bh[NT];
#pragma unroll
    for (int j = 0; j < NT; ++j) {
        float x0 = bx[j * 4 + 0], y0 = bx[j * 4 + 1];
        float x1 = bx[j * 4 + 2], y1 = bx[j * 4 + 3];
        cx[j] = ((x0 + x1) * 0.5f) * (1.f / 512.f);
        cy[j] = ((y0 + y1) * 0.5f) * (1.f / 512.f);
        bw[j] = fabsf(x1 - x0) * (1.f / 512.f);
        bh[j] = fabsf(y1 - y0) * (1.f / 512.f);
    }
    float dist[NT];
#pragma unroll
    for (int j = 0; j < NT; ++j) {
        float dx = cx[n] - cx[j], dy = cy[n] - cy[j];
        float dxx = dx * dx, dyy = dy * dy;
        dist[j] = (j == n) ? __builtin_inff() : (dxx + dyy);
    }
    float ocx = cx[n], ocy = cy[n], obw = bw[n], obh = bh[n];
#pragma unroll
    for (int k = 0; k < KNN; ++k) {
        int best = 0; float bd = __builtin_inff();
#pragma unroll
        for (int j = 0; j < NT; ++j)
            if (dist[j] < bd) { bd = dist[j]; best = j; }   // strict <  == lowest-index tie-break
        float fx = 0, fy = 0, fw = 0, fh = 0;
#pragma unroll
        for (int j = 0; j < NT; ++j)
            if (j == best) { fx = cx[j]; fy = cy[j]; fw = bw[j]; fh = bh[j]; dist[j] = __builtin_inff(); }
        size_t o = (size_t)gid * 20 + k * 4;
        rel[o + 0] = fx - ocx;
        rel[o + 1] = fy - ocy;
        rel[o + 2] = fw - obw;
        rel[o + 3] = fh - obh;
    }
}

// ---------------------------------------------------------------------------
// gemm_in: x0 = rel @ w_in^T + b_in   [MTOT,20] @ [20,512], f32 -> bf16
// ---------------------------------------------------------------------------
__global__ void gemm_in(const float* __restrict__ rel, const float* __restrict__ w_in,
                        const float* __restrict__ b_in, bf* __restrict__ x0)
{
    __shared__ __align__(16) float relS[128][20];
    int tid = threadIdx.x;
    size_t tok0 = (size_t)blockIdx.x * 128;
    for (int i = tid; i < 128 * 20; i += 256)
        relS[i / 20][i % 20] = rel[tok0 * 20 + i];
    float w0[20], w1r[20];
#pragma unroll
    for (int j = 0; j < 20; ++j) {
        w0[j]  = w_in[tid * 20 + j];
        w1r[j] = w_in[(tid + 256) * 20 + j];
    }
    float bias0 = b_in[tid], bias1 = b_in[tid + 256];
    __syncthreads();
    for (int tk = 0; tk < 128; ++tk) {
        const float4* rp = (const float4*)relS[tk];
        float a0 = bias0, a1 = bias1;
#pragma unroll
        for (int v4 = 0; v4 < 5; ++v4) {
            float4 rv = rp[v4];
            a0 += rv.x * w0[v4 * 4 + 0] + rv.y * w0[v4 * 4 + 1]
                + rv.z * w0[v4 * 4 + 2] + rv.w * w0[v4 * 4 + 3];
            a1 += rv.x * w1r[v4 * 4 + 0] + rv.y * w1r[v4 * 4 + 1]
                + rv.z * w1r[v4 * 4 + 2] + rv.w * w1r[v4 * 4 + 3];
        }
        x0[(tok0 + tk) * 512 + tid]       = tob(a0);
        x0[(tok0 + tk) * 512 + tid + 256] = tob(a1);
    }
}

// ---------------------------------------------------------------------------
// gemm2: out[m,n] = sum_k A[m,k]*Bt[n,k] (+epilogue), M=163840, N=K=512
// BM=128, BN=256, BK=32. 512 thr = 8 waves (2m x 4n), 64x64 out each.
// LDS 48 KB double-buffered; launch_bounds(512,4): <=128 VGPR (NO spill;
// (512,6) would force an 85-VGPR cap and spill the 64-VGPR accumulator).
// Counted-vmcnt pipeline (T4): issue stage(next), s_waitcnt vmcnt(3)
// (never 0 in loop), raw s_barrier; next-tile loads stay in flight
// across the barrier.
// LDS layout [kc][row][8] chunked: linear gld_lds dest + conflict-free b128.
// EPI: 0 none | 1 f32 bias + exact gelu | 2 f32 bias | 3 add prev out
// ---------------------------------------------------------------------------
template <int EPI>
__launch_bounds__(512, 4)
__global__ void gemm2(const bf* __restrict__ A, const bf* __restrict__ Bt,
                      bf* __restrict__ out, const float* __restrict__ biasf)
{
    __shared__ __align__(16) bf As[2][4096];   // [buf][kc(4)][row(128)][8]
    __shared__ __align__(16) bf Bs[2][8192];   // [buf][kc(4)][row(256)][8]
    int tid = threadIdx.x;
    int w = tid >> 6, l = tid & 63;
    int lq = l >> 4, lr = l & 15;
    size_t m0 = (size_t)blockIdx.y * 128;
    int n0 = blockIdx.x * 256;
    int wm = (w & 1) * 64, wn = (w >> 1) * 64;
    floatx4 acc[4][4] = {};

    // per-thread global staging addrs (A: 1 load, B: 2 loads per tile)
    const bf* Ag = A + (m0 + (size_t)(tid & 127)) * 512 + (tid >> 7) * 8;
    const bf* Bg = Bt + (size_t)(n0 + (tid & 255)) * 512 + (tid >> 8) * 8;

    auto stage = [&](int buf, int kt) {
        GLD_LDS(Ag + kt * 32,      &As[buf][w * 512]);          // As[c=tid][8], c=kc*128+row
        GLD_LDS(Bg + kt * 32,      &Bs[buf][w * 512]);          // Bs[c=tid]
        GLD_LDS(Bg + kt * 32 + 16, &Bs[buf][4096 + w * 512]);   // Bs[c=512+tid]
    };

    stage(0, 0);
#pragma unroll 2
    for (int kt = 0; kt < 16; ++kt) {
        int cur = kt & 1;
        if (kt < 15) {
            stage(cur ^ 1, kt + 1);
            asm volatile("s_waitcnt vmcnt(3)" ::: "memory");   // cur's 3 loads done; next 3 in flight
        } else {
            asm volatile("s_waitcnt vmcnt(0)" ::: "memory");
        }
        __builtin_amdgcn_sched_barrier(0);
        __builtin_amdgcn_s_barrier();          // all waves' cur tile in LDS
        __builtin_amdgcn_sched_barrier(0);

        const bf* as = &As[cur][(lq * 128 + wm + lr) * 8];
        const bf* bs = &Bs[cur][(lq * 256 + wn + lr) * 8];
        bfrag8 af[4], bfv[4];
#pragma unroll
        for (int i = 0; i < 4; ++i) af[i] = *(const bfrag8*)(as + i * 128);
#pragma unroll
        for (int j = 0; j < 4; ++j) bfv[j] = *(const bfrag8*)(bs + j * 128);
#pragma unroll
        for (int i = 0; i < 4; ++i)
#pragma unroll
            for (int j = 0; j < 4; ++j)
                acc[i][j] = __builtin_amdgcn_mfma_f32_16x16x32_bf16(af[i], bfv[j], acc[i][j], 0, 0, 0);

        if (kt < 15) {
            __builtin_amdgcn_sched_barrier(0);
            __builtin_amdgcn_s_barrier();      // all waves done reading cur before overwrite
        }
    }

#pragma unroll
    for (int i = 0; i < 4; ++i)
#pragma unroll
        for (int j = 0; j < 4; ++j) {
            int col = n0 + wn + j * 16 + lr;
#pragma unroll
            for (int r = 0; r < 4; ++r) {
                size_t row = m0 + wm + i * 16 + lq * 4 + r;
                float v = acc[i][j][r];
                if (EPI == 1) { v += biasf[col]; v = 0.5f * v * (1.f + erff(v * 0.70710678118654752f)); }
                if (EPI == 2) v += biasf[col];
                if (EPI == 3) v += tof(out[row * 512 + col]);
                out[row * 512 + col] = tob(v);
            }
        }
}

// ---------------------------------------------------------------------------
// scoresz: fused scores + softmax + zmix. One wave per batch.
// Phase 1: S = t_b @ x0_b^T + xu, softmax -> att in LDS.
// Phase 2: z = att @ x0_b written IN-PLACE into t rows of this batch.
// (Cross-block reads of neighbor t rows are -inf masked -> race-safe.)
// ---------------------------------------------------------------------------
__global__ void scoresz(bf* __restrict__ t, const bf* __restrict__ x0,
                        const float* __restrict__ uvec_h)
{
    __shared__ float as[4][256];
    int tid = threadIdx.x;
    int w = tid >> 6, l = tid & 63;
    int lq = l >> 4, lr = l & 15;
    size_t b = (size_t)blockIdx.x * 4 + w;
    bf* trow = t + (b * NT + lr) * 512;          // lr>=10 overruns into pad/next rows (masked)
    const bf* xrow = x0 + (b * NT + lr) * 512;
    floatx4 acc = {0.f, 0.f, 0.f, 0.f};
    float xu = 0.f;
#pragma unroll
    for (int kk = 0; kk < 16; ++kk) {
        bfrag8 a  = *(const bfrag8*)(trow + kk * 32 + lq * 8);
        bfrag8 bb = *(const bfrag8*)(xrow + kk * 32 + lq * 8);
        acc = __builtin_amdgcn_mfma_f32_16x16x32_bf16(a, bb, acc, 0, 0, 0);
#pragma unroll
        for (int jj = 0; jj < 8; ++jj)
            xu += (float)bb[jj] * uvec_h[kk * 32 + lq * 8 + jj];
    }
    xu += __shfl_xor(xu, 16);
    xu += __shfl_xor(xu, 32);    // xu for column j = lr
    bool jvalid = (lr < NT);
#pragma unroll
    for (int r = 0; r < 4; ++r) {
        float v = jvalid ? (acc[r] + xu) : -__builtin_inff();
        float m = v;
        m = fmaxf(m, __shfl_xor(m, 1)); m = fmaxf(m, __shfl_xor(m, 2));
        m = fmaxf(m, __shfl_xor(m, 4)); m = fmaxf(m, __shfl_xor(m, 8));
        float e = jvalid ? __expf(v - m) : 0.f;
        float s = e;
        s += __shfl_xor(s, 1); s += __shfl_xor(s, 2);
        s += __shfl_xor(s, 4); s += __shfl_xor(s, 8);
        float a = e / s;
        as[w][(lq * 4 + r) * 16 + lr] = a;   // att[i][j]; rows i>=10 garbage, never read
    }
    __syncthreads();
    // phase 2: z[i][dslice] = sum_j att[i][j] * x0[b][j][dslice], dslice = l*8..l*8+7
    bfrag8 xj[NT];
#pragma unroll
    for (int j = 0; j < NT; ++j)
        xj[j] = *(const bfrag8*)(x0 + (b * NT + j) * 512 + l * 8);
#pragma unroll
    for (int i = 0; i < NT; ++i) {
        float z[8] = {};
#pragma unroll
        for (int j = 0; j < NT; ++j) {
            float a = as[w][i * 16 + j];
#pragma unroll
            for (int q = 0; q < 8; ++q) z[q] += a * (float)xj[j][q];
        }
        bfrag8 zv;
#pragma unroll
        for (int q = 0; q < 8; ++q) zv[q] = tob(z[q]);
        *(bfrag8*)(t + (b * NT + i) * 512 + l * 8) = zv;
    }
}

// ---------------------------------------------------------------------------
// ln: xout = LN(xin + yin) * w + b   (one wave per token), f32 LN params
// ---------------------------------------------------------------------------
__global__ void ln_kernel(const bf* __restrict__ xin, const bf* __restrict__ yin,
                          const float* __restrict__ w, const float* __restrict__ bias,
                          bf* __restrict__ xout)
{
    int tid = threadIdx.x;
    int wv = tid >> 6, l = tid & 63;
    size_t tok = (size_t)blockIdx.x * 4 + wv;
    bfrag8 xv = *(const bfrag8*)(xin + tok * 512 + l * 8);
    bfrag8 yv = *(const bfrag8*)(yin + tok * 512 + l * 8);
    float v[8]; float s = 0.f;
#pragma unroll
    for (int i = 0; i < 8; ++i) { v[i] = (float)xv[i] + (float)yv[i]; s += v[i]; }
#pragma unroll
    for (int m = 1; m < 64; m <<= 1) s += __shfl_xor(s, m);
    float mu = s * (1.f / 512.f);
    float vs = 0.f;
#pragma unroll
    for (int i = 0; i < 8; ++i) { float d = v[i] - mu; vs += d * d; }
#pragma unroll
    for (int m = 1; m < 64; m <<= 1) vs += __shfl_xor(vs, m);
    float r = rsqrtf(vs * (1.f / 512.f) + 1e-5f);
    bfrag8 ov;
#pragma unroll
    for (int i = 0; i < 8; ++i) {
        int d = l * 8 + i;
        ov[i] = tob((v[i] - mu) * r * w[d] + bias[d]);
    }
    *(bfrag8*)(xout + tok * 512 + l * 8) = ov;
}

// ---------------------------------------------------------------------------
// final: out = LN( LN(x1 + ff2; ln2); lnf )   -> f32 output
// ---------------------------------------------------------------------------
__global__ void final_kernel(const bf* __restrict__ x1, const bf* __restrict__ ff2,
                             const float* __restrict__ w2, const float* __restrict__ b2,
                             const float* __restrict__ wf, const float* __restrict__ bfi,
                             float* __restrict__ out)
{
    int tid = threadIdx.x;
    int wv = tid >> 6, l = tid & 63;
    size_t tok = (size_t)blockIdx.x * 4 + wv;
    bfrag8 xv = *(const bfrag8*)(x1 + tok * 512 + l * 8);
    bfrag8 yv = *(const bfrag8*)(ff2 + tok * 512 + l * 8);
    float v[8]; float s = 0.f;
#pragma unroll
    for (int i = 0; i < 8; ++i) { v[i] = (float)xv[i] + (float)yv[i]; s += v[i]; }
#pragma unroll
    for (int m = 1; m < 64; m <<= 1) s += __shfl_xor(s, m);
    float mu = s * (1.f / 512.f);
    float vs = 0.f;
#pragma unroll
    for (int i = 0; i < 8; ++i) { float d = v[i] - mu; vs += d * d; }
#pragma unroll
    for (int m = 1; m < 64; m <<= 1) vs += __shfl_xor(vs, m);
    float r = rsqrtf(vs * (1.f / 512.f) + 1e-5f);
    float u[8]; float s2 = 0.f;
#pragma unroll
    for (int i = 0; i < 8; ++i) {
        int d = l * 8 + i;
        u[i] = (v[i] - mu) * r * w2[d] + b2[d];
        s2 += u[i];
    }
#pragma unroll
    for (int m = 1; m < 64; m <<= 1) s2 += __shfl_xor(s2, m);
    float mu2 = s2 * (1.f / 512.f);
    float vs2 = 0.f;
#pragma unroll
    for (int i = 0; i < 8; ++i) { float d = u[i] - mu2; vs2 += d * d; }
#pragma unroll
    for (int m = 1; m < 64; m <<= 1) vs2 += __shfl_xor(vs2, m);
    float r2 = rsqrtf(vs2 * (1.f / 512.f) + 1e-5f);
    float4 o0, o1;
    float* op = (float*)&o0;
#pragma unroll
    for (int i = 0; i < 4; ++i) op[i] = (u[i] - mu2) * r2 * wf[l * 8 + i] + bfi[l * 8 + i];
    op = (float*)&o1;
#pragma unroll
    for (int i = 0; i < 4; ++i) op[i] = (u[4 + i] - mu2) * r2 * wf[l * 8 + 4 + i] + bfi[l * 8 + 4 + i];
    *(float4*)(out + tok * 512 + l * 8) = o0;
    *(float4*)(out + tok * 512 + l * 8 + 4) = o1;
}

// ---------------------------------------------------------------------------
extern "C" void kernel_launch(void* const* d_in, const int* in_sizes, int n_in,
                              void* d_out, int out_size, void* d_ws, size_t ws_size,
                              hipStream_t stream)
{
    const float* boxes = (const float*)d_in[0];
    const float* w_in  = (const float*)d_in[1];
    const float* b_in  = (const float*)d_in[2];
    const float* wqkv  = (const float*)d_in[3];
    const float* bqkv  = (const float*)d_in[4];
    const float* wo    = (const float*)d_in[5];
    const float* bo    = (const float*)d_in[6];
    const float* ln1w  = (const float*)d_in[7];
    const float* ln1b  = (const float*)d_in[8];
    const float* w1    = (const float*)d_in[9];
    const float* b1    = (const float*)d_in[10];
    const float* w2    = (const float*)d_in[11];
    const float* b2    = (const float*)d_in[12];
    const float* ln2w  = (const float*)d_in[13];
    const float* ln2b  = (const float*)d_in[14];
    const float* lnfw  = (const float*)d_in[15];
    const float* lnfb  = (const float*)d_in[16];
    float* out = (float*)d_out;

    char* ws = (char*)d_ws;
    // layout (bytes), total ≈ 519.6 MB:
    bf*    At     = (bf*)(ws + 0);                            //  1,048,576
    bf*    Ct     = (bf*)(ws + 1048576);                      //  1,048,576
    bf*    W1b    = (bf*)(ws + 2097152);                      //  524,288
    bf*    W2b    = (bf*)(ws + 2621440);                      //  524,288
    float* wconst = (float*)(ws + 3145728);                   //  2,048
    float* uvec   = (float*)(ws + 3147776);                   //  4,096
    bf*    x0     = (bf*)(ws + 16259072);                     //  (MTOT+16)*512*2
    bf*    t      = (bf*)(ws + 184047616);                    //  (MTOT+16)*512*2
    bf*    y      = (bf*)(ws + 351836160);                    //  MTOT*512*2
    float* rel    = (float*)(ws + 184047616);                 //  overlays t (disjoint lifetime)

    dim3 gblk(256);
    dim3 ggemm(2, MTOT / 128);   // BN=256 -> 2 col panels, BM=128 -> 1280 row panels

    prep_folds<<<4097, gblk, 0, stream>>>(wqkv, bqkv, wo, bo, At, Ct, wconst, uvec);
    cvt_w<<<256, gblk, 0, stream>>>(w1, W1b);
    cvt_w<<<256, gblk, 0, stream>>>(w2, W2b);
    rel_kernel<<<(MTOT + 255) / 256, gblk, 0, stream>>>(boxes, rel);
    gemm_in<<<MTOT / 128, gblk, 0, stream>>>(rel, w_in, b_in, x0);

    // head 0: scores precursor, fused softmax+zmix (z0 in-place in t), attn-out
    gemm2<0><<<ggemm, 512, 0, stream>>>(x0, At, t, nullptr);
    scoresz<<<B_ / 4, gblk, 0, stream>>>(t, x0, uvec);
    gemm2<2><<<ggemm, 512, 0, stream>>>(t, Ct, y, wconst);
    // head 1
    gemm2<0><<<ggemm, 512, 0, stream>>>(x0, At + 262144, t, nullptr);
    scoresz<<<B_ / 4, gblk, 0, stream>>>(t, x0, uvec + 512);
    gemm2<3><<<ggemm, 512, 0, stream>>>(t, Ct + 262144, y, nullptr);
    // x1 = LN(x0 + y) (in place into x0)
    ln_kernel<<<MTOT / 4, gblk, 0, stream>>>(x0, y, ln1w, ln1b, x0);
    // ff1 = gelu(x1@w1^T + b1) -> t ; ff2 = ff1@w2^T + b2 -> y
    gemm2<1><<<ggemm, 512, 0, stream>>>(x0, W1b, t, b1);
    gemm2<2><<<ggemm, 512, 0, stream>>>(t, W2b, y, b2);
    // out = LN(LN(x1+ff2; ln2); lnf)
    final_kernel<<<MTOT / 4, gblk, 0, stream>>>(x0, y, ln2w, ln2b, lnfw, lnfb, out);
}